// Round 2
// baseline (740.265 us; speedup 1.0000x reference)
//
#include <hip/hip_runtime.h>
#include <stdint.h>

#define T_FULL 2049
#define T_OUT  2048
#define NB     256
#define ND     128
#define U_DIM  32768      // NB*ND
#define NBLK   (T_OUT * 4)

typedef __bf16 bf16x8 __attribute__((ext_vector_type(8)));
typedef __bf16 bf16x2 __attribute__((ext_vector_type(2)));
typedef float  f32x4  __attribute__((ext_vector_type(4)));

// async global->LDS, 16B per lane. LDS dest = uniform base + lane*16.
__device__ __forceinline__ void gl_lds16(const void* g, void* l) {
  void* gnc = const_cast<void*>(g);
  __builtin_amdgcn_global_load_lds(
      (__attribute__((address_space(1))) unsigned int*)gnc,
      (__attribute__((address_space(3))) unsigned int*)l, 16, 0, 0);
}

// ---------------------------------------------------------------------------
// Kernel 1: pred is a 32768 x 2049 fp32 matrix M[u][t] (u = b*128+d).
// Produce H[t][u], L[t][u] bf16 hi/lo split, t-major (each t-slice is the
// 256x128 row-major operand for the per-t GEMM).
// ---------------------------------------------------------------------------
__global__ __launch_bounds__(256) void transpose_split(
    const float* __restrict__ pred, __bf16* __restrict__ H, __bf16* __restrict__ L) {
  __shared__ float tile[128][33];  // +1 pad breaks power-of-2 stride
  const int u0 = blockIdx.x << 7;  // 128 u per block
  const int t0 = blockIdx.y << 5;  // 32 t per block
  const int tid = threadIdx.x;
  {
    const int tx  = tid & 7;   // 8 thr * 4 elems = 32 t
    const int row = tid >> 3;  // 32 rows/pass
#pragma unroll
    for (int p2 = 0; p2 < 4; ++p2) {
      const int ul = row + (p2 << 5);
      const float* src = pred + (size_t)(u0 + ul) * T_FULL + t0;
#pragma unroll
      for (int e = 0; e < 4; ++e) {
        const int tl = (tx << 2) + e;
        tile[ul][tl] = (t0 + tl < T_FULL) ? src[tl] : 0.f;
      }
    }
  }
  __syncthreads();
  {
    const int j   = tid & 63;  // 64 lanes * 2 u = 128 u (one wave = one t-row)
    const int trw = tid >> 6;
#pragma unroll
    for (int q2 = 0; q2 < 8; ++q2) {
      const int tl = (q2 << 2) + trw;
      const int tg = t0 + tl;
      if (tg >= T_FULL) continue;
      const float x0 = tile[(j << 1) + 0][tl];
      const float x1 = tile[(j << 1) + 1][tl];
      const __bf16 h0 = (__bf16)x0;
      const __bf16 h1 = (__bf16)x1;
      const __bf16 l0 = (__bf16)(x0 - (float)h0);
      const __bf16 l1 = (__bf16)(x1 - (float)h1);
      const size_t base = (size_t)tg * U_DIM + u0 + (j << 1);
      bf16x2 hv; hv.x = h0; hv.y = h1;
      bf16x2 lv; lv.x = l0; lv.y = l1;
      *(bf16x2*)(H + base) = hv;
      *(bf16x2*)(L + base) = lv;
    }
  }
}

// ---------------------------------------------------------------------------
// Kernel 2: per block: one t, 64 b-rows (b0..b0+63), all 256 c-cols.
// Split-bf16 GEMM: S = Ah*Bh^T + Ah*Bl^T + Al*Bh^T  (AlBl ~2^-18, dropped).
// Fused epilogue (max-stabilized so fp32 never overflows, unlike the naive
// reference): m = max_c S; loss = (m - fz) + log(sum_c exp(S - m)).
//
// LDS (40KB): Bh[256x32] 16K | Bl 16K | Ah[64x32] 4K | Al 4K, all slot-
// swizzled: element (row,c8) -> slot s = (row&15)*4 + ((c8 + ((row&15)>>1))&3)
// within 1KB group (row>>4). Write side (global_load_lds lane*16) and read
// side (ds_read_b128 frags) are both <=2-way bank conflicts.
// ---------------------------------------------------------------------------
__global__ __launch_bounds__(256) void gemm_lse(
    const __bf16* __restrict__ H, const __bf16* __restrict__ L,
    float* __restrict__ partials) {
  __shared__ __align__(16) char lds[40960];
  __bf16* Ah = (__bf16*)(lds + 32768);
  __bf16* Al = (__bf16*)(lds + 36864);
  __bf16* Bh = (__bf16*)(lds);
  __bf16* Bl = (__bf16*)(lds + 16384);

  const int blk = blockIdx.x;
  const int t   = blk >> 2;
  const int b0  = (blk & 3) << 6;
  const int tid  = threadIdx.x;
  const int w    = tid >> 6;   // wave 0..3 -> rows b0+w*16..+15
  const int lane = tid & 63;

  const __bf16* Ha = H + (size_t)t * U_DIM;
  const __bf16* La = L + (size_t)t * U_DIM;
  const __bf16* Hb = H + (size_t)(t + 1) * U_DIM;
  const __bf16* Lb = L + (size_t)(t + 1) * U_DIM;

  // staging decode: lane -> (row-in-group, global 8-elem chunk)
  const int srow   = lane >> 2;
  const int schunk = ((lane & 3) - (lane >> 3)) & 3;
  // frag read decode
  const int q  = lane >> 4;
  const int rr = lane & 15;
  const int slot = (rr << 2) | ((q + (rr >> 1)) & 3);

  f32x4 acc[16];
#pragma unroll
  for (int i = 0; i < 16; ++i) acc[i] = f32x4{0.f, 0.f, 0.f, 0.f};

  const int arow_g = b0 + (w << 4) + srow;

  for (int kc = 0; kc < 4; ++kc) {
    const int koff = kc << 5;
    __syncthreads();
#pragma unroll
    for (int i = 0; i < 4; ++i) {
      const int g  = (w << 2) + i;                       // B group 0..15
      const size_t goff = (size_t)((g << 4) + srow) * ND + koff + (schunk << 3);
      gl_lds16(Hb + goff, lds + g * 1024);
      gl_lds16(Lb + goff, lds + 16384 + g * 1024);
    }
    {
      const size_t aoff = (size_t)arow_g * ND + koff + (schunk << 3);
      gl_lds16(Ha + aoff, lds + 32768 + w * 1024);
      gl_lds16(La + aoff, lds + 36864 + w * 1024);
    }
    __syncthreads();

    const bf16x8 ah = *(const bf16x8*)(Ah + (w << 9) + (slot << 3));
    const bf16x8 al = *(const bf16x8*)(Al + (w << 9) + (slot << 3));
#pragma unroll
    for (int ct = 0; ct < 16; ++ct) {
      const bf16x8 bh = *(const bf16x8*)(Bh + (ct << 9) + (slot << 3));
      const bf16x8 bl = *(const bf16x8*)(Bl + (ct << 9) + (slot << 3));
      acc[ct] = __builtin_amdgcn_mfma_f32_16x16x32_bf16(ah, bh, acc[ct], 0, 0, 0);
      acc[ct] = __builtin_amdgcn_mfma_f32_16x16x32_bf16(ah, bl, acc[ct], 0, 0, 0);
      acc[ct] = __builtin_amdgcn_mfma_f32_16x16x32_bf16(al, bh, acc[ct], 0, 0, 0);
    }
  }

  __syncthreads();  // all LDS reads done; reuse LDS for epilogue scratch
  float* fzsh  = (float*)lds;          // 64 floats: fz per local row
  float* redsh = (float*)(lds + 256);  // 16 floats: per (wave,quad) partials

  // diag S[b,b]: for wave w it lives in col-tile ctd = b0/16 + w, at lanes
  // where (rr>>2)==q, register rr&3, local row rr.
  const int ctd = (b0 >> 4) + w;
  if ((rr >> 2) == q) {
    float dv = 0.f;
    const int rm = rr & 3;
#pragma unroll
    for (int ct = 0; ct < 16; ++ct)
      if (ct == ctd) {
        const float e0 = acc[ct][0], e1 = acc[ct][1], e2 = acc[ct][2], e3 = acc[ct][3];
        dv = (rm == 0) ? e0 : (rm == 1) ? e1 : (rm == 2) ? e2 : e3;
      }
    fzsh[(w << 4) + rr] = dv;
  }
  __syncthreads();

  // row max of S (over all 256 cols): per-lane max over ct, then over the
  // 16 lanes (rr=0..15) sharing this row group.
  float mx[4];
#pragma unroll
  for (int r = 0; r < 4; ++r) mx[r] = -3.0e38f;
#pragma unroll
  for (int ct = 0; ct < 16; ++ct)
#pragma unroll
    for (int r = 0; r < 4; ++r) mx[r] = fmaxf(mx[r], acc[ct][r]);
#pragma unroll
  for (int off = 1; off < 16; off <<= 1)
#pragma unroll
    for (int r = 0; r < 4; ++r) mx[r] = fmaxf(mx[r], __shfl_xor(mx[r], off, 64));

  // p = sum_c exp(S - m)  (in [1, 256], never overflows)
  float p[4];
#pragma unroll
  for (int r = 0; r < 4; ++r) p[r] = 0.f;
#pragma unroll
  for (int ct = 0; ct < 16; ++ct)
#pragma unroll
    for (int r = 0; r < 4; ++r) p[r] += expf(acc[ct][r] - mx[r]);
#pragma unroll
  for (int off = 1; off < 16; off <<= 1)
#pragma unroll
    for (int r = 0; r < 4; ++r) p[r] += __shfl_xor(p[r], off, 64);

  if (rr == 0) {
    // loss_row = (m - fz) + log(p); fz cancels inside the exp.
    float s = 0.f;
#pragma unroll
    for (int r = 0; r < 4; ++r) {
      const float fzv = fzsh[(w << 4) + (q << 2) + r];
      s += (mx[r] - fzv) + logf(p[r]);
    }
    redsh[(w << 2) + q] = s;
  }
  __syncthreads();
  if (tid == 0) {
    float s = 0.f;
#pragma unroll
    for (int i = 0; i < 16; ++i) s += redsh[i];
    partials[blk] = s;
  }
}

// ---------------------------------------------------------------------------
// Kernel 3: deterministic reduction of NBLK partials in fp64, scale by 1/(T*B)
// ---------------------------------------------------------------------------
__global__ __launch_bounds__(256) void final_reduce(
    const float* __restrict__ partials, float* __restrict__ out) {
  __shared__ double sh[256];
  double s = 0.0;
  for (int i = threadIdx.x; i < NBLK; i += 256) s += (double)partials[i];
  sh[threadIdx.x] = s;
  __syncthreads();
  for (int st = 128; st > 0; st >>= 1) {
    if ((int)threadIdx.x < st) sh[threadIdx.x] += sh[threadIdx.x + st];
    __syncthreads();
  }
  if (threadIdx.x == 0) out[0] = (float)(sh[0] * (1.0 / ((double)T_OUT * NB)));
}

extern "C" void kernel_launch(void* const* d_in, const int* in_sizes, int n_in,
                              void* d_out, int out_size, void* d_ws, size_t ws_size,
                              hipStream_t stream) {
  const float* pred = (const float*)d_in[0];
  float* out = (float*)d_out;
  char* ws = (char*)d_ws;
  __bf16* H = (__bf16*)ws;                                          // 134.3 MB
  __bf16* L = (__bf16*)(ws + (size_t)T_FULL * U_DIM * 2);           // 134.3 MB
  float* partials = (float*)(ws + (size_t)T_FULL * U_DIM * 4);      // 32 KB

  dim3 tgrid(U_DIM / 128, (T_FULL + 31) / 32);
  transpose_split<<<tgrid, 256, 0, stream>>>(pred, H, L);
  gemm_lse<<<NBLK, 256, 0, stream>>>(H, L, partials);
  final_reduce<<<1, 256, 0, stream>>>(partials, out);
}

// Round 3
// 715.166 us; speedup vs baseline: 1.0351x; 1.0351x over previous
//
#include <hip/hip_runtime.h>
#include <stdint.h>

#define T_FULL 2049
#define T_OUT  2048
#define NB     256
#define ND     128
#define U_DIM  32768      // NB*ND
#define NBLK   (T_OUT * 4)

typedef __bf16 bf16x8 __attribute__((ext_vector_type(8)));
typedef float  f32x4  __attribute__((ext_vector_type(4)));

// async global->LDS. LDS dest = uniform base + lane*size.
__device__ __forceinline__ void gl_lds16(const void* g, void* l) {
  void* gnc = const_cast<void*>(g);
  __builtin_amdgcn_global_load_lds(
      (__attribute__((address_space(1))) unsigned int*)gnc,
      (__attribute__((address_space(3))) unsigned int*)l, 16, 0, 0);
}
__device__ __forceinline__ void gl_lds4(const void* g, void* l) {
  void* gnc = const_cast<void*>(g);
  __builtin_amdgcn_global_load_lds(
      (__attribute__((address_space(1))) unsigned int*)gnc,
      (__attribute__((address_space(3))) unsigned int*)l, 4, 0, 0);
}

// ---------------------------------------------------------------------------
// Kernel 1 v3: transpose+split via global_load_lds (no VGPR round-trip -> MLP
// limited by vmcnt, not by the 8-VGPR starvation rocprof showed in v2).
// Block: 64u x 64t fp32 tile. LDS row stride 65 floats: staging (lane*4
// contiguous per row) is conflict-free; transposed read is exactly 2-way
// (bank = (r + tl) % 32, 8 r-groups x 8 tl = all 32 banks x2) = free (m136).
// Covers t in [0, 2048): the t=2048 slice is a separate tail kernel (reading
// a full 64-t row there would run 252 B past the exactly-page-aligned input).
// ---------------------------------------------------------------------------
#define TROW 65  // floats per LDS row
__global__ __launch_bounds__(256) void transpose_split(
    const float* __restrict__ pred, __bf16* __restrict__ H, __bf16* __restrict__ L) {
  __shared__ __align__(16) float tile[64 * TROW];  // 16.6 KB
  const int u0 = blockIdx.x << 6;  // 64 u per block
  const int t0 = blockIdx.y << 6;  // 64 t per block (t0+63 <= 2047)
  const int tid  = threadIdx.x;
  const int w    = tid >> 6;
  const int lane = tid & 63;

  // stage: wave w loads rows 16w..16w+15; one 256B async load per row
  {
    const float* src = pred + (size_t)(u0 + (w << 4)) * T_FULL + t0 + lane;
#pragma unroll
    for (int i = 0; i < 16; ++i) {
      gl_lds4(src + (size_t)i * T_FULL, &tile[((w << 4) + i) * TROW]);
    }
  }
  __syncthreads();

  // output: lane owns u-chunk (lane&7)*8..+7; tl = w*16 + p*8 + (lane>>3)
  const int uc = (lane & 7) << 3;
#pragma unroll
  for (int p = 0; p < 2; ++p) {
    const int tl = (w << 4) + (p << 3) + (lane >> 3);
    float x[8];
#pragma unroll
    for (int k = 0; k < 8; ++k) x[k] = tile[(uc + k) * TROW + tl];
    bf16x8 hv, lv;
#pragma unroll
    for (int k = 0; k < 8; ++k) {
      const __bf16 h = (__bf16)x[k];
      hv[k] = h;
      lv[k] = (__bf16)(x[k] - (float)h);
    }
    const size_t base = (size_t)(t0 + tl) * U_DIM + u0 + uc;
    *(bf16x8*)(H + base) = hv;
    *(bf16x8*)(L + base) = lv;
  }
}

// tail: the t = 2048 slice (stride-2049 scalar reads, 32768 elements)
__global__ __launch_bounds__(256) void transpose_tail(
    const float* __restrict__ pred, __bf16* __restrict__ H, __bf16* __restrict__ L) {
  const int u = (blockIdx.x << 8) + threadIdx.x;
  const float x = pred[(size_t)u * T_FULL + T_OUT];
  const __bf16 h = (__bf16)x;
  H[(size_t)T_OUT * U_DIM + u] = h;
  L[(size_t)T_OUT * U_DIM + u] = (__bf16)(x - (float)h);
}

// ---------------------------------------------------------------------------
// Kernel 2: per block: one t, 64 b-rows (b0..b0+63), all 256 c-cols.
// Split-bf16 GEMM: S = Ah*Bh^T + Ah*Bl^T + Al*Bh^T  (AlBl ~2^-18, dropped).
// Fused epilogue (max-stabilized): m = max_c S; loss = (m-fz) + log(sum exp(S-m)).
// ---------------------------------------------------------------------------
__global__ __launch_bounds__(256) void gemm_lse(
    const __bf16* __restrict__ H, const __bf16* __restrict__ L,
    float* __restrict__ partials) {
  __shared__ __align__(16) char lds[40960];
  __bf16* Ah = (__bf16*)(lds + 32768);
  __bf16* Al = (__bf16*)(lds + 36864);
  __bf16* Bh = (__bf16*)(lds);
  __bf16* Bl = (__bf16*)(lds + 16384);

  const int blk = blockIdx.x;
  const int t   = blk >> 2;
  const int b0  = (blk & 3) << 6;
  const int tid  = threadIdx.x;
  const int w    = tid >> 6;   // wave 0..3 -> rows b0+w*16..+15
  const int lane = tid & 63;

  const __bf16* Ha = H + (size_t)t * U_DIM;
  const __bf16* La = L + (size_t)t * U_DIM;
  const __bf16* Hb = H + (size_t)(t + 1) * U_DIM;
  const __bf16* Lb = L + (size_t)(t + 1) * U_DIM;

  // staging decode: lane -> (row-in-group, global 8-elem chunk)
  const int srow   = lane >> 2;
  const int schunk = ((lane & 3) - (lane >> 3)) & 3;
  // frag read decode
  const int q  = lane >> 4;
  const int rr = lane & 15;
  const int slot = (rr << 2) | ((q + (rr >> 1)) & 3);

  f32x4 acc[16];
#pragma unroll
  for (int i = 0; i < 16; ++i) acc[i] = f32x4{0.f, 0.f, 0.f, 0.f};

  const int arow_g = b0 + (w << 4) + srow;

  for (int kc = 0; kc < 4; ++kc) {
    const int koff = kc << 5;
    __syncthreads();
#pragma unroll
    for (int i = 0; i < 4; ++i) {
      const int g  = (w << 2) + i;                       // B group 0..15
      const size_t goff = (size_t)((g << 4) + srow) * ND + koff + (schunk << 3);
      gl_lds16(Hb + goff, lds + g * 1024);
      gl_lds16(Lb + goff, lds + 16384 + g * 1024);
    }
    {
      const size_t aoff = (size_t)arow_g * ND + koff + (schunk << 3);
      gl_lds16(Ha + aoff, lds + 32768 + w * 1024);
      gl_lds16(La + aoff, lds + 36864 + w * 1024);
    }
    __syncthreads();

    const bf16x8 ah = *(const bf16x8*)(Ah + (w << 9) + (slot << 3));
    const bf16x8 al = *(const bf16x8*)(Al + (w << 9) + (slot << 3));
#pragma unroll
    for (int ct = 0; ct < 16; ++ct) {
      const bf16x8 bh = *(const bf16x8*)(Bh + (ct << 9) + (slot << 3));
      const bf16x8 bl = *(const bf16x8*)(Bl + (ct << 9) + (slot << 3));
      acc[ct] = __builtin_amdgcn_mfma_f32_16x16x32_bf16(ah, bh, acc[ct], 0, 0, 0);
      acc[ct] = __builtin_amdgcn_mfma_f32_16x16x32_bf16(ah, bl, acc[ct], 0, 0, 0);
      acc[ct] = __builtin_amdgcn_mfma_f32_16x16x32_bf16(al, bh, acc[ct], 0, 0, 0);
    }
  }

  __syncthreads();  // all LDS reads done; reuse LDS for epilogue scratch
  float* fzsh  = (float*)lds;          // 64 floats: fz per local row
  float* redsh = (float*)(lds + 256);  // 16 floats: per (wave,quad) partials

  // diag S[b,b]: for wave w it lives in col-tile ctd = b0/16 + w, at lanes
  // where (rr>>2)==q, register rr&3, local row rr.
  const int ctd = (b0 >> 4) + w;
  if ((rr >> 2) == q) {
    float dv = 0.f;
    const int rm = rr & 3;
#pragma unroll
    for (int ct = 0; ct < 16; ++ct)
      if (ct == ctd) {
        const float e0 = acc[ct][0], e1 = acc[ct][1], e2 = acc[ct][2], e3 = acc[ct][3];
        dv = (rm == 0) ? e0 : (rm == 1) ? e1 : (rm == 2) ? e2 : e3;
      }
    fzsh[(w << 4) + rr] = dv;
  }
  __syncthreads();

  // row max of S over all 256 cols
  float mx[4];
#pragma unroll
  for (int r = 0; r < 4; ++r) mx[r] = -3.0e38f;
#pragma unroll
  for (int ct = 0; ct < 16; ++ct)
#pragma unroll
    for (int r = 0; r < 4; ++r) mx[r] = fmaxf(mx[r], acc[ct][r]);
#pragma unroll
  for (int off = 1; off < 16; off <<= 1)
#pragma unroll
    for (int r = 0; r < 4; ++r) mx[r] = fmaxf(mx[r], __shfl_xor(mx[r], off, 64));

  // p = sum_c exp(S - m)  (in [1, 256], never overflows)
  float p[4];
#pragma unroll
  for (int r = 0; r < 4; ++r) p[r] = 0.f;
#pragma unroll
  for (int ct = 0; ct < 16; ++ct)
#pragma unroll
    for (int r = 0; r < 4; ++r) p[r] += __expf(acc[ct][r] - mx[r]);
#pragma unroll
  for (int off = 1; off < 16; off <<= 1)
#pragma unroll
    for (int r = 0; r < 4; ++r) p[r] += __shfl_xor(p[r], off, 64);

  if (rr == 0) {
    float s = 0.f;
#pragma unroll
    for (int r = 0; r < 4; ++r) {
      const float fzv = fzsh[(w << 4) + (q << 2) + r];
      s += (mx[r] - fzv) + logf(p[r]);
    }
    redsh[(w << 2) + q] = s;
  }
  __syncthreads();
  if (tid == 0) {
    float s = 0.f;
#pragma unroll
    for (int i = 0; i < 16; ++i) s += redsh[i];
    partials[blk] = s;
  }
}

// ---------------------------------------------------------------------------
// Kernel 3: deterministic reduction of NBLK partials in fp64, scale by 1/(T*B)
// ---------------------------------------------------------------------------
__global__ __launch_bounds__(256) void final_reduce(
    const float* __restrict__ partials, float* __restrict__ out) {
  __shared__ double sh[256];
  double s = 0.0;
  for (int i = threadIdx.x; i < NBLK; i += 256) s += (double)partials[i];
  sh[threadIdx.x] = s;
  __syncthreads();
  for (int st = 128; st > 0; st >>= 1) {
    if ((int)threadIdx.x < st) sh[threadIdx.x] += sh[threadIdx.x + st];
    __syncthreads();
  }
  if (threadIdx.x == 0) out[0] = (float)(sh[0] * (1.0 / ((double)T_OUT * NB)));
}

extern "C" void kernel_launch(void* const* d_in, const int* in_sizes, int n_in,
                              void* d_out, int out_size, void* d_ws, size_t ws_size,
                              hipStream_t stream) {
  const float* pred = (const float*)d_in[0];
  float* out = (float*)d_out;
  char* ws = (char*)d_ws;
  __bf16* H = (__bf16*)ws;                                          // 134.3 MB
  __bf16* L = (__bf16*)(ws + (size_t)T_FULL * U_DIM * 2);           // 134.3 MB
  float* partials = (float*)(ws + (size_t)T_FULL * U_DIM * 4);      // 32 KB

  dim3 tgrid(U_DIM / 64, T_OUT / 64);  // t in [0,2048)
  transpose_split<<<tgrid, 256, 0, stream>>>(pred, H, L);
  transpose_tail<<<U_DIM / 256, 256, 0, stream>>>(pred, H, L);
  gemm_lse<<<NBLK, 256, 0, stream>>>(H, L, partials);
  final_reduce<<<1, 256, 0, stream>>>(partials, out);
}

// Round 4
// 530.035 us; speedup vs baseline: 1.3966x; 1.3493x over previous
//
#include <hip/hip_runtime.h>
#include <stdint.h>

#define T_FULL 2049
#define T_OUT  2048
#define NB     256
#define ND     128
#define U_DIM  32768      // NB*ND
#define NBLK   (T_OUT * 4)

typedef __bf16 bf16x8 __attribute__((ext_vector_type(8)));
typedef float  f32x4  __attribute__((ext_vector_type(4)));

// async global->LDS. LDS dest = uniform base + lane*size.
__device__ __forceinline__ void gl_lds16(const void* g, void* l) {
  void* gnc = const_cast<void*>(g);
  __builtin_amdgcn_global_load_lds(
      (__attribute__((address_space(1))) unsigned int*)gnc,
      (__attribute__((address_space(3))) unsigned int*)l, 16, 0, 0);
}
__device__ __forceinline__ void gl_lds4(const void* g, void* l) {
  void* gnc = const_cast<void*>(g);
  __builtin_amdgcn_global_load_lds(
      (__attribute__((address_space(1))) unsigned int*)gnc,
      (__attribute__((address_space(3))) unsigned int*)l, 4, 0, 0);
}

// ---------------------------------------------------------------------------
// Kernel 1 v5: transpose to bf16 (hi only). Block = 64u x 128t.
// LDS tile stride 129 floats (129 % 32 == 1): staging writes (lane*4
// contiguous) conflict-free; transposed reads bank=(u+t)%32 -> exactly
// 2-way across 64 lanes = free (m136). 33 KB LDS -> 4 blocks/CU; 32
// outstanding gl_lds4 per wave -> MLP-rich, HBM-BW-bound.
// ---------------------------------------------------------------------------
#define TSTRIDE 129
__global__ __launch_bounds__(256) void transpose_split(
    const float* __restrict__ pred, __bf16* __restrict__ H) {
  __shared__ __align__(16) float tile[64 * TSTRIDE];  // 33 KB
  const int u0 = blockIdx.x << 6;   // 64 u per block
  const int t0 = blockIdx.y << 7;   // 128 t per block (t0+127 <= 2047)
  const int tid  = threadIdx.x;
  const int w    = tid >> 6;
  const int lane = tid & 63;

  // stage: wave w loads rows 16w..16w+15, two 256B segments each
  {
    const float* src = pred + (size_t)(u0 + (w << 4)) * T_FULL + t0 + lane;
#pragma unroll
    for (int i = 0; i < 16; ++i) {
      const int row = (w << 4) + i;
      gl_lds4(src + (size_t)i * T_FULL,      &tile[row * TSTRIDE]);
      gl_lds4(src + (size_t)i * T_FULL + 64, &tile[row * TSTRIDE + 64]);
    }
  }
  __syncthreads();

  // output: lane owns u-chunk (lane&7)*8..+7; wave w owns t-range w*32..+31
  const int uc = (lane & 7) << 3;
#pragma unroll
  for (int p = 0; p < 4; ++p) {
    const int tl = (w << 5) + (p << 3) + (lane >> 3);
    float x[8];
#pragma unroll
    for (int k = 0; k < 8; ++k) x[k] = tile[(uc + k) * TSTRIDE + tl];
    bf16x8 hv;
#pragma unroll
    for (int k = 0; k < 8; ++k) hv[k] = (__bf16)x[k];
    *(bf16x8*)(H + (size_t)(t0 + tl) * U_DIM + u0 + uc) = hv;
  }
}

// tail: the t = 2048 slice (stride-2049 scalar reads, 32768 elements)
__global__ __launch_bounds__(256) void transpose_tail(
    const float* __restrict__ pred, __bf16* __restrict__ H) {
  const int u = (blockIdx.x << 8) + threadIdx.x;
  H[(size_t)T_OUT * U_DIM + u] = (__bf16)pred[(size_t)u * T_FULL + T_OUT];
}

// ---------------------------------------------------------------------------
// Kernel 2 v4 (pure bf16): block = one t, 64 b-rows, 256 c-cols, single
// K=128 stage. B (256x128 = 64 KB) in LDS, row-major 256 B rows with
// chunk-XOR swizzle: stored[row][c] = global[row][c ^ (row&7)] (16B chunks).
// Fragment reads then hit 8 distinct bank-quads x 2 lanes = 2-way = free.
// A fragments load straight from global into registers (16 B x 4 per lane;
// A(t) rows == B(t) rows of the 4 blocks at t-1 -> L2-warm). One barrier
// pair for the whole GEMM. Epilogue max-stabilized as before.
// ---------------------------------------------------------------------------
__global__ __launch_bounds__(256) void gemm_lse(
    const __bf16* __restrict__ H, float* __restrict__ partials) {
  __shared__ __align__(16) char lds[65536];
  __bf16* Bs = (__bf16*)lds;

  const int blk = blockIdx.x;
  const int t   = blk >> 2;
  const int b0  = (blk & 3) << 6;
  const int tid  = threadIdx.x;
  const int w    = tid >> 6;   // wave 0..3 -> rows b0+w*16..+15
  const int lane = tid & 63;

  const __bf16* Ha = H + (size_t)t * U_DIM;
  const __bf16* Hb = H + (size_t)(t + 1) * U_DIM;

  const int q  = lane >> 4;
  const int rr = lane & 15;

  // ---- B staging: wave w stages groups g = w*16..w*16+15 (4 rows each) ----
  {
    const int srow4 = lane >> 4;    // row within 4-row group
    const int cst   = lane & 15;    // LDS chunk this lane's data lands in
#pragma unroll
    for (int i = 0; i < 16; ++i) {
      const int g   = (w << 4) + i;
      const int row = (g << 2) + srow4;
      const int cg  = cst ^ (row & 7);            // global chunk to fetch
      gl_lds16(Hb + (size_t)row * ND + (cg << 3), lds + (g << 10));
    }
  }

  // ---- A fragments: direct global->VGPR, row = b0 + w*16 + rr ----
  bf16x8 af[4];
  {
    const __bf16* arow = Ha + (size_t)(b0 + (w << 4) + rr) * ND;
#pragma unroll
    for (int ks = 0; ks < 4; ++ks)
      af[ks] = *(const bf16x8*)(arow + (ks << 5) + (q << 3));
  }

  f32x4 acc[16];
#pragma unroll
  for (int i = 0; i < 16; ++i) acc[i] = f32x4{0.f, 0.f, 0.f, 0.f};

  __syncthreads();  // drains gl_lds16 (compiler emits vmcnt(0) before barrier)

#pragma unroll
  for (int ks = 0; ks < 4; ++ks) {
    const int cix = ((ks << 2) + q) ^ (rr & 7);   // swizzled chunk
#pragma unroll
    for (int ct = 0; ct < 16; ++ct) {
      const bf16x8 bv = *(const bf16x8*)(Bs + (size_t)((ct << 4) + rr) * ND + (cix << 3));
      acc[ct] = __builtin_amdgcn_mfma_f32_16x16x32_bf16(af[ks], bv, acc[ct], 0, 0, 0);
    }
  }

  __syncthreads();  // all LDS reads done; reuse LDS for epilogue scratch
  float* fzsh  = (float*)lds;          // 64 floats: fz per local row
  float* redsh = (float*)(lds + 256);  // 16 floats: per (wave,quad) partials

  // diag S[b,b]: for wave w it lives in col-tile ctd = b0/16 + w, at lanes
  // where (rr>>2)==q, register rr&3, local row rr.
  const int ctd = (b0 >> 4) + w;
  if ((rr >> 2) == q) {
    float dv = 0.f;
    const int rm = rr & 3;
#pragma unroll
    for (int ct = 0; ct < 16; ++ct)
      if (ct == ctd) {
        const float e0 = acc[ct][0], e1 = acc[ct][1], e2 = acc[ct][2], e3 = acc[ct][3];
        dv = (rm == 0) ? e0 : (rm == 1) ? e1 : (rm == 2) ? e2 : e3;
      }
    fzsh[(w << 4) + rr] = dv;
  }
  __syncthreads();

  // row max of S over all 256 cols
  float mx[4];
#pragma unroll
  for (int r = 0; r < 4; ++r) mx[r] = -3.0e38f;
#pragma unroll
  for (int ct = 0; ct < 16; ++ct)
#pragma unroll
    for (int r = 0; r < 4; ++r) mx[r] = fmaxf(mx[r], acc[ct][r]);
#pragma unroll
  for (int off = 1; off < 16; off <<= 1)
#pragma unroll
    for (int r = 0; r < 4; ++r) mx[r] = fmaxf(mx[r], __shfl_xor(mx[r], off, 64));

  // p = sum_c exp(S - m)  (in [1, 256], never overflows)
  float p[4];
#pragma unroll
  for (int r = 0; r < 4; ++r) p[r] = 0.f;
#pragma unroll
  for (int ct = 0; ct < 16; ++ct)
#pragma unroll
    for (int r = 0; r < 4; ++r) p[r] += __expf(acc[ct][r] - mx[r]);
#pragma unroll
  for (int off = 1; off < 16; off <<= 1)
#pragma unroll
    for (int r = 0; r < 4; ++r) p[r] += __shfl_xor(p[r], off, 64);

  if (rr == 0) {
    float s = 0.f;
#pragma unroll
    for (int r = 0; r < 4; ++r) {
      const float fzv = fzsh[(w << 4) + (q << 2) + r];
      s += (mx[r] - fzv) + logf(p[r]);
    }
    redsh[(w << 2) + q] = s;
  }
  __syncthreads();
  if (tid == 0) {
    float s = 0.f;
#pragma unroll
    for (int i = 0; i < 16; ++i) s += redsh[i];
    partials[blk] = s;
  }
}

// ---------------------------------------------------------------------------
// Kernel 3: deterministic reduction of NBLK partials in fp64, scale by 1/(T*B)
// ---------------------------------------------------------------------------
__global__ __launch_bounds__(256) void final_reduce(
    const float* __restrict__ partials, float* __restrict__ out) {
  __shared__ double sh[256];
  double s = 0.0;
  for (int i = threadIdx.x; i < NBLK; i += 256) s += (double)partials[i];
  sh[threadIdx.x] = s;
  __syncthreads();
  for (int st = 128; st > 0; st >>= 1) {
    if ((int)threadIdx.x < st) sh[threadIdx.x] += sh[threadIdx.x + st];
    __syncthreads();
  }
  if (threadIdx.x == 0) out[0] = (float)(sh[0] * (1.0 / ((double)T_OUT * NB)));
}

extern "C" void kernel_launch(void* const* d_in, const int* in_sizes, int n_in,
                              void* d_out, int out_size, void* d_ws, size_t ws_size,
                              hipStream_t stream) {
  const float* pred = (const float*)d_in[0];
  float* out = (float*)d_out;
  char* ws = (char*)d_ws;
  __bf16* H = (__bf16*)ws;                                      // 134.3 MB
  float* partials = (float*)(ws + (size_t)T_FULL * U_DIM * 2);  // 32 KB

  dim3 tgrid(U_DIM / 64, T_OUT / 128);  // t in [0,2048)
  transpose_split<<<tgrid, 256, 0, stream>>>(pred, H);
  transpose_tail<<<U_DIM / 256, 256, 0, stream>>>(pred, H);
  gemm_lse<<<NBLK, 256, 0, stream>>>(H, partials);
  final_reduce<<<1, 256, 0, stream>>>(partials, out);
}

// Round 5
// 513.782 us; speedup vs baseline: 1.4408x; 1.0316x over previous
//
#include <hip/hip_runtime.h>
#include <stdint.h>

#define T_FULL 2049
#define T_OUT  2048
#define NB     256
#define ND     128
#define U_DIM  32768      // NB*ND
#define NBLK   (T_OUT * 4)

typedef __bf16 bf16x8 __attribute__((ext_vector_type(8)));
typedef float  f32x4  __attribute__((ext_vector_type(4)));

// async global->LDS. LDS dest = uniform base + lane*size.
__device__ __forceinline__ void gl_lds16(const void* g, void* l) {
  void* gnc = const_cast<void*>(g);
  __builtin_amdgcn_global_load_lds(
      (__attribute__((address_space(1))) unsigned int*)gnc,
      (__attribute__((address_space(3))) unsigned int*)l, 16, 0, 0);
}

// ---------------------------------------------------------------------------
// Kernel 1 v6: transpose to bf16 via VGPR staging (4 independent dwordx4
// loads/thread -> ds_write_b128 with progressive vmcnt, no full drain).
// Block = 64u x 64t, LDS 64x65 fp32 (16.6 KB) -> ~8 blocks/CU. Read side:
// 64-B segments; write side: 128-B segments, LDS reads exactly 2-way
// (bank = (u + t) % 32) = free (m136).
// ---------------------------------------------------------------------------
#define TP 65
__global__ __launch_bounds__(256) void transpose_split(
    const float* __restrict__ pred, __bf16* __restrict__ H) {
  __shared__ __align__(16) float tile[64 * TP];
  const int u0 = blockIdx.x << 6;   // 64 u per block
  const int t0 = blockIdx.y << 6;   // 64 t per block (t0+63 <= 2047)
  const int tid  = threadIdx.x;
  const int w    = tid >> 6;
  const int l    = tid & 63;

  // stage: thread owns row r = w*16 + (l>>2), chunks c = (l&3) + 4i (16B each)
  const int r  = (w << 4) + (l >> 2);
  const int c0 = l & 3;
  const float* src = pred + (size_t)(u0 + r) * T_FULL + t0 + (c0 << 2);
  float4 v[4];
#pragma unroll
  for (int i = 0; i < 4; ++i) v[i] = *(const float4*)(src + (i << 4));
#pragma unroll
  for (int i = 0; i < 4; ++i)
    *(float4*)&tile[r * TP + (c0 << 2) + (i << 4)] = v[i];
  __syncthreads();

  // output: lane owns u-chunk (l&7)*8..+7; tl = w*16 + p*8 + (l>>3)
  const int uc = (l & 7) << 3;
#pragma unroll
  for (int p = 0; p < 2; ++p) {
    const int tl = (w << 4) + (p << 3) + (l >> 3);
    float x[8];
#pragma unroll
    for (int k = 0; k < 8; ++k) x[k] = tile[(uc + k) * TP + tl];
    bf16x8 hv;
#pragma unroll
    for (int k = 0; k < 8; ++k) hv[k] = (__bf16)x[k];
    *(bf16x8*)(H + (size_t)(t0 + tl) * U_DIM + u0 + uc) = hv;
  }
}

// tail: the t = 2048 slice (stride-2049 scalar reads, 32768 elements)
__global__ __launch_bounds__(256) void transpose_tail(
    const float* __restrict__ pred, __bf16* __restrict__ H) {
  const int u = (blockIdx.x << 8) + threadIdx.x;
  H[(size_t)T_OUT * U_DIM + u] = (__bf16)pred[(size_t)u * T_FULL + T_OUT];
}

// ---------------------------------------------------------------------------
// Kernel 2 v4 (pure bf16): block = one t, 64 b-rows, 256 c-cols, single
// K=128 stage. B (256x128 = 64 KB) in LDS with chunk-XOR swizzle; A
// fragments straight global->VGPR. Epilogue max-stabilized.
// ---------------------------------------------------------------------------
__global__ __launch_bounds__(256) void gemm_lse(
    const __bf16* __restrict__ H, float* __restrict__ partials) {
  __shared__ __align__(16) char lds[65536];
  __bf16* Bs = (__bf16*)lds;

  const int blk = blockIdx.x;
  const int t   = blk >> 2;
  const int b0  = (blk & 3) << 6;
  const int tid  = threadIdx.x;
  const int w    = tid >> 6;   // wave 0..3 -> rows b0+w*16..+15
  const int lane = tid & 63;

  const __bf16* Ha = H + (size_t)t * U_DIM;
  const __bf16* Hb = H + (size_t)(t + 1) * U_DIM;

  const int q  = lane >> 4;
  const int rr = lane & 15;

  // ---- B staging: wave w stages groups g = w*16..w*16+15 (4 rows each) ----
  {
    const int srow4 = lane >> 4;    // row within 4-row group
    const int cst   = lane & 15;    // LDS chunk this lane's data lands in
#pragma unroll
    for (int i = 0; i < 16; ++i) {
      const int g   = (w << 4) + i;
      const int row = (g << 2) + srow4;
      const int cg  = cst ^ (row & 7);            // global chunk to fetch
      gl_lds16(Hb + (size_t)row * ND + (cg << 3), lds + (g << 10));
    }
  }

  // ---- A fragments: direct global->VGPR, row = b0 + w*16 + rr ----
  bf16x8 af[4];
  {
    const __bf16* arow = Ha + (size_t)(b0 + (w << 4) + rr) * ND;
#pragma unroll
    for (int ks = 0; ks < 4; ++ks)
      af[ks] = *(const bf16x8*)(arow + (ks << 5) + (q << 3));
  }

  f32x4 acc[16];
#pragma unroll
  for (int i = 0; i < 16; ++i) acc[i] = f32x4{0.f, 0.f, 0.f, 0.f};

  __syncthreads();  // drains gl_lds16

#pragma unroll
  for (int ks = 0; ks < 4; ++ks) {
    const int cix = ((ks << 2) + q) ^ (rr & 7);   // swizzled chunk
#pragma unroll
    for (int ct = 0; ct < 16; ++ct) {
      const bf16x8 bv = *(const bf16x8*)(Bs + (size_t)((ct << 4) + rr) * ND + (cix << 3));
      acc[ct] = __builtin_amdgcn_mfma_f32_16x16x32_bf16(af[ks], bv, acc[ct], 0, 0, 0);
    }
  }

  __syncthreads();  // all LDS reads done; reuse LDS for epilogue scratch
  float* fzsh  = (float*)lds;          // 64 floats: fz per local row
  float* redsh = (float*)(lds + 256);  // 16 floats: per (wave,quad) partials

  // diag S[b,b]: for wave w it lives in col-tile ctd = b0/16 + w, at lanes
  // where (rr>>2)==q, register rr&3, local row rr.
  const int ctd = (b0 >> 4) + w;
  if ((rr >> 2) == q) {
    float dv = 0.f;
    const int rm = rr & 3;
#pragma unroll
    for (int ct = 0; ct < 16; ++ct)
      if (ct == ctd) {
        const float e0 = acc[ct][0], e1 = acc[ct][1], e2 = acc[ct][2], e3 = acc[ct][3];
        dv = (rm == 0) ? e0 : (rm == 1) ? e1 : (rm == 2) ? e2 : e3;
      }
    fzsh[(w << 4) + rr] = dv;
  }
  __syncthreads();

  // row max of S over all 256 cols
  float mx[4];
#pragma unroll
  for (int r = 0; r < 4; ++r) mx[r] = -3.0e38f;
#pragma unroll
  for (int ct = 0; ct < 16; ++ct)
#pragma unroll
    for (int r = 0; r < 4; ++r) mx[r] = fmaxf(mx[r], acc[ct][r]);
#pragma unroll
  for (int off = 1; off < 16; off <<= 1)
#pragma unroll
    for (int r = 0; r < 4; ++r) mx[r] = fmaxf(mx[r], __shfl_xor(mx[r], off, 64));

  // p = sum_c exp(S - m)  (in [1, 256], never overflows)
  float p[4];
#pragma unroll
  for (int r = 0; r < 4; ++r) p[r] = 0.f;
#pragma unroll
  for (int ct = 0; ct < 16; ++ct)
#pragma unroll
    for (int r = 0; r < 4; ++r) p[r] += __expf(acc[ct][r] - mx[r]);
#pragma unroll
  for (int off = 1; off < 16; off <<= 1)
#pragma unroll
    for (int r = 0; r < 4; ++r) p[r] += __shfl_xor(p[r], off, 64);

  if (rr == 0) {
    float s = 0.f;
#pragma unroll
    for (int r = 0; r < 4; ++r) {
      const float fzv = fzsh[(w << 4) + (q << 2) + r];
      s += (mx[r] - fzv) + logf(p[r]);
    }
    redsh[(w << 2) + q] = s;
  }
  __syncthreads();
  if (tid == 0) {
    float s = 0.f;
#pragma unroll
    for (int i = 0; i < 16; ++i) s += redsh[i];
    partials[blk] = s;
  }
}

// ---------------------------------------------------------------------------
// Kernel 3: deterministic reduction of NBLK partials in fp64, scale by 1/(T*B)
// ---------------------------------------------------------------------------
__global__ __launch_bounds__(256) void final_reduce(
    const float* __restrict__ partials, float* __restrict__ out) {
  __shared__ double sh[256];
  double s = 0.0;
  for (int i = threadIdx.x; i < NBLK; i += 256) s += (double)partials[i];
  sh[threadIdx.x] = s;
  __syncthreads();
  for (int st = 128; st > 0; st >>= 1) {
    if ((int)threadIdx.x < st) sh[threadIdx.x] += sh[threadIdx.x + st];
    __syncthreads();
  }
  if (threadIdx.x == 0) out[0] = (float)(sh[0] * (1.0 / ((double)T_OUT * NB)));
}

extern "C" void kernel_launch(void* const* d_in, const int* in_sizes, int n_in,
                              void* d_out, int out_size, void* d_ws, size_t ws_size,
                              hipStream_t stream) {
  const float* pred = (const float*)d_in[0];
  float* out = (float*)d_out;
  char* ws = (char*)d_ws;
  __bf16* H = (__bf16*)ws;                                      // 134.3 MB
  float* partials = (float*)(ws + (size_t)T_FULL * U_DIM * 2);  // 32 KB

  dim3 tgrid(U_DIM / 64, T_OUT / 64);  // t in [0,2048)
  transpose_split<<<tgrid, 256, 0, stream>>>(pred, H);
  transpose_tail<<<U_DIM / 256, 256, 0, stream>>>(pred, H);
  gemm_lse<<<NBLK, 256, 0, stream>>>(H, partials);
  final_reduce<<<1, 256, 0, stream>>>(partials, out);
}